// Round 7
// baseline (216.747 us; speedup 1.0000x reference)
//
#include <hip/hip_runtime.h>
#include <cstdint>
#include <cstddef>

// LSTM cell: B=4096, IN=1024, H=1024
//   ifgo = h @ Wh^T + bh + x @ Wx^T    [4096 x 4096]
//   i,f,g,o = split(ifgo); c' = sig(f)*c + sig(i)*tanh(g); h' = o*tanh(c')
//
// Pipeline (2 dispatches):
//   1. convert: fp32->bf16, 8 floats/thread, K=2048 layout (A_cat=[h|x],
//      W_cat=[Wh|Wx]) with W rows permuted p=((j>>4)<<6)|(gate<<4)|(j&15).
//   2. gemm: 256x256 tile, BK=64, 8 waves, PIPELINED-PHASE schedule:
//      each phase = {16 MFMA (operands loaded LAST phase) || ds_reads for
//      NEXT quadrant || 2 stage gload_lds} + uniform clump
//      {lgkm(0); vmcnt(6); barrier}.  A 2-deep + B 3-deep LDS (160 KiB),
//      every stage drained exactly 4 phases after issue (full HBM cover),
//      sched_barrier(0) pins MFMA-before-reads, XOR-swizzled LDS
//      (conflicts=0), XCD swizzle, setprio.  Fused LSTM gate epilogue.

#define NB   4096
#define KH   1024
#define KK   2048
#define ARR_ELEMS 4194304  // 4096*1024
#define NKT  32            // K tiles of 64

typedef __bf16 bf16x8 __attribute__((ext_vector_type(8)));
typedef float  f32x4  __attribute__((ext_vector_type(4)));

__device__ inline unsigned short f2bf(float f) {
    union { float f; unsigned int u; } v; v.f = f;
    unsigned int u = v.u;
    u += 0x7FFFu + ((u >> 16) & 1u);   // RNE
    return (unsigned short)(u >> 16);
}

__device__ inline float fsig(float v)  { return __builtin_amdgcn_rcpf(1.f + __expf(-v)); }
__device__ inline float ftanh(float v) { return 1.f - 2.f * __builtin_amdgcn_rcpf(1.f + __expf(2.f * v)); }

// ---------------------------------------------------------------- convert ---
__global__ void convert_kernel(const float* __restrict__ h, const float* __restrict__ x,
                               const float* __restrict__ Wh, const float* __restrict__ Wx,
                               unsigned short* __restrict__ A, unsigned short* __restrict__ W) {
    int idx = blockIdx.x * 256 + threadIdx.x;       // 0 .. 2M-1
    int arr = idx >> 19;
    int off = (idx & 0x7FFFF) << 3;
    const float* src = (arr == 0) ? h : (arr == 1) ? x : (arr == 2) ? Wh : Wx;
    float4 v0 = *(const float4*)(src + off);
    float4 v1 = *(const float4*)(src + off + 4);
    uint4 packed;
    packed.x = (unsigned int)f2bf(v0.x) | ((unsigned int)f2bf(v0.y) << 16);
    packed.y = (unsigned int)f2bf(v0.z) | ((unsigned int)f2bf(v0.w) << 16);
    packed.z = (unsigned int)f2bf(v1.x) | ((unsigned int)f2bf(v1.y) << 16);
    packed.w = (unsigned int)f2bf(v1.z) | ((unsigned int)f2bf(v1.w) << 16);

    int row = off >> 10;
    int col = off & 1023;
    unsigned short* dst;
    size_t dstOff;
    if (arr < 2) {                                  // A_cat: [h | x] per row
        dst = A;
        dstOff = (size_t)row * KK + (arr == 1 ? 1024 : 0) + col;
    } else {                                        // W_cat: permuted rows
        int g = row >> 10, j = row & 1023;
        int p = ((j >> 4) << 6) | (g << 4) | (j & 15);
        dst = W;
        dstOff = (size_t)p * KK + (arr == 3 ? 1024 : 0) + col;
    }
    *(uint4*)(dst + dstOff) = packed;
}

// ------------------------------------------------------------------- gemm ---
// 512 threads = 8 waves (2 M-halves x 4 N-quarters). Wave output 128x64.
// LDS: As 2-deep, Bs 3-deep (32 KiB each buffer, 160 KiB total), XOR swizzle
// phys_byte = row*128 + (kbyte ^ ((row&7)<<4)); staging keeps LDS linear
// (global_load_lds) with pre-swizzled per-lane GLOBAL source.
//
// Per K-tile T (bufA = T%2, bufB = T%3), 4 phases; each phase:
//   [setprio(1); 16 MFMA (operands loaded in a PREVIOUS phase); setprio(0);
//    sched_barrier(0); ds_reads for next quadrant; 2 stage gload_lds;
//    s_waitcnt vmcnt(6) lgkmcnt(0); s_barrier]
//   Q1: mfma a03xb01(cur); read b23(T)<-Bs[T%3];   stage B(T+2)h0->Bs[(T+2)%3]
//   Q2: mfma a03xb23;      read a47(T)<-As[T%2];   stage B(T+2)h1
//   Q3: mfma a47xb23;      read a03(T+1)<-As[~T];  stage A(T+2){ch0,2}->As[T%2]
//   Q4: mfma a47xb01(cur); read b01(T+1)->nxt set; stage A(T+2){ch1,3}
//
// Hazard invariants (verified per-region):
//  - reads: b23(T) published Q4(T-2)/Q1(T-1); a47(T) drained Q3(T-1)-end;
//    a03(T+1) drained Q2(T)-end; b01(T+1) drained Q1(T)-end.  All precede use.
//  - stages target dead regions: Bs[(T+2)%3]=Bs[(T-1)%3] died Q1(T-1)-end
//    (its b01 was read at Q4(T-2), b23 at Q1(T-1)); As[T%2] dies Q2(T)-end
//    (a03(T) read at Q3(T-1), a47(T) at Q2(T)) -> stage at Q3/Q4.
//  - vmcnt(6): 2 loads issued/phase, 8 outstanding pre-drain; the drained
//    group was issued exactly 4 phases (~2500 cy) earlier.  Never 0.
//  - A-chunk regrouping: chunks {0,2} = a03 rows (both wr halves), {1,3} =
//    a47 rows, so drained groups align with read regions.
__global__ __launch_bounds__(512, 2) void gemm_kernel(const unsigned short* __restrict__ A,
                            const unsigned short* __restrict__ W,
                            const float* __restrict__ bh,
                            const float* __restrict__ c,
                            float* __restrict__ out) {
    __shared__ __align__(16) unsigned short As[2 * 16384];   // 64 KiB
    __shared__ __align__(16) unsigned short Bs[3 * 16384];   // 96 KiB

    const int tid  = threadIdx.x;
    const int wave = tid >> 6;
    const int lane = tid & 63;

    // T1: 256 blocks, 8 XCDs -> contiguous 32-tile chunks per XCD
    const int bid   = (int)blockIdx.x;
    const int swz   = (bid & 7) * 32 + (bid >> 3);
    const int tileM = swz >> 4;        // 0..15
    const int tileN = swz & 15;        // 0..15

    const int wr  = wave >> 2;         // 0..1  M half
    const int wc  = wave & 3;          // 0..3  N quarter
    const int fr  = lane & 15;
    const int fk2 = (lane >> 4) << 4;  // fragment byte k-offset {0,16,32,48}

    // ---- staging: per-thread pre-swizzled global source pointers ----------
    // chunk i covers LDS phys bytes [(i*512+tid)*16, +16) = rows i*64..i*64+63
    const unsigned short* pa[4];
    const unsigned short* pb[4];
    #pragma unroll
    for (int i = 0; i < 4; ++i) {
        const int P   = (i * 512 + tid) * 16;
        const int L   = P ^ (((P >> 7) & 7) << 4);
        const int row = L >> 7;
        const int kk  = (L & 127) >> 1;
        pa[i] = A + (size_t)(tileM * 256 + row) * KK + kk;
        pb[i] = W + (size_t)(tileN * 256 + row) * KK + kk;
    }

    // ---- compute-side swizzled LDS byte offsets ---------------------------
    const int swzm = (fr & 7) << 4;
    int offA[8], offB[4];
    #pragma unroll
    for (int i = 0; i < 8; ++i)
        offA[i] = (wr * 128 + i * 16 + fr) * 128 + (fk2 ^ swzm);
    #pragma unroll
    for (int j = 0; j < 4; ++j)
        offB[j] = (wc * 64 + j * 16 + fr) * 128 + (fk2 ^ swzm);
    // second K=32 panel: offset ^ 64

    f32x4 acc[8][4] = {};
    bf16x8 a03[4][2], a47[4][2], b23[2][2], b01A[2][2], b01B[2][2];

#define STAGE_B_H(H, KT, BUF) do { \
    const size_t _ko = (size_t)(KT) * 64; \
    _Pragma("unroll") \
    for (int _i = 2*(H); _i < 2*(H)+2; ++_i) \
        __builtin_amdgcn_global_load_lds( \
            (const __attribute__((address_space(1))) void*)(pb[_i] + _ko), \
            (__attribute__((address_space(3))) void*)(Bs + (BUF) * 16384 + _i * 4096 + wave * 512), 16, 0, 0); \
} while (0)

#define STAGE_A_Q(Q, KT, BUF) do { \
    const size_t _ko = (size_t)(KT) * 64; \
    _Pragma("unroll") \
    for (int _k = 0; _k < 2; ++_k) { \
        const int _i = (Q) + 2 * _k;   /* Q=0 -> chunks {0,2}=a03 rows */ \
        __builtin_amdgcn_global_load_lds( \
            (const __attribute__((address_space(1))) void*)(pa[_i] + _ko), \
            (__attribute__((address_space(3))) void*)(As + (BUF) * 16384 + _i * 4096 + wave * 512), 16, 0, 0); \
    } \
} while (0)

#define READ_A(dst, base, AsB) do { \
    _Pragma("unroll") \
    for (int _i = 0; _i < 4; ++_i) { \
        dst[_i][0] = *(const bf16x8*)((AsB) + offA[(base) + _i]); \
        dst[_i][1] = *(const bf16x8*)((AsB) + (offA[(base) + _i] ^ 64)); \
    } \
} while (0)

#define READ_B(dst, base, BsB) do { \
    _Pragma("unroll") \
    for (int _j = 0; _j < 2; ++_j) { \
        dst[_j][0] = *(const bf16x8*)((BsB) + offB[(base) + _j]); \
        dst[_j][1] = *(const bf16x8*)((BsB) + (offB[(base) + _j] ^ 64)); \
    } \
} while (0)

#define MFMAQ(af, bf, IB, JB) do { \
    __builtin_amdgcn_s_setprio(1); \
    _Pragma("unroll") \
    for (int _i = 0; _i < 4; ++_i) \
        _Pragma("unroll") \
        for (int _j = 0; _j < 2; ++_j) \
            _Pragma("unroll") \
            for (int _s = 0; _s < 2; ++_s) \
                acc[(IB) + _i][(JB) + _j] = __builtin_amdgcn_mfma_f32_16x16x32_bf16( \
                    af[_i][_s], bf[_j][_s], acc[(IB) + _i][(JB) + _j], 0, 0, 0); \
    __builtin_amdgcn_s_setprio(0); \
    __builtin_amdgcn_sched_barrier(0); \
} while (0)

#define CLUMP do { \
    asm volatile("s_waitcnt vmcnt(6) lgkmcnt(0)" ::: "memory"); \
    __builtin_amdgcn_s_barrier(); \
} while (0)

// TILEBODY(T, AB=T%2, BB=T%3, ABn=(T+1)%2, BBn=(T+1)%3, BBs=(T+2)%3,
//          bcur/bnxt = b01 register set parity)
#define TILEBODY(T, AB, BB, ABn, BBn, BBs, bcur, bnxt) do { \
    const char* AsT = (const char*)As + (AB) * 32768; \
    const char* AsN = (const char*)As + (ABn) * 32768; \
    const char* BsT = (const char*)Bs + (BB) * 32768; \
    const char* BsN = (const char*)Bs + (BBn) * 32768; \
    const int _t2 = ((T) + 2 <= NKT - 1) ? ((T) + 2) : (NKT - 1); \
    /* Q1 */ \
    MFMAQ(a03, bcur, 0, 0); \
    READ_B(b23, 2, BsT); \
    STAGE_B_H(0, _t2, BBs); \
    CLUMP; \
    /* Q2 */ \
    MFMAQ(a03, b23, 0, 2); \
    READ_A(a47, 4, AsT); \
    STAGE_B_H(1, _t2, BBs); \
    CLUMP; \
    /* Q3 */ \
    MFMAQ(a47, b23, 4, 2); \
    READ_A(a03, 0, AsN); \
    STAGE_A_Q(0, _t2, AB); \
    CLUMP; \
    /* Q4 */ \
    MFMAQ(a47, bcur, 4, 0); \
    READ_B(bnxt, 0, BsN); \
    STAGE_A_Q(1, _t2, AB); \
    CLUMP; \
} while (0)

    // ---- prologue: establish the steady 8-outstanding queue ---------------
    // issue order: B(0)[4], A(0)[4] (drained), then B(1)h0,h1, A(1){02},{13}
    STAGE_B_H(0, 0, 0); STAGE_B_H(1, 0, 0);
    STAGE_A_Q(0, 0, 0); STAGE_A_Q(1, 0, 0);
    STAGE_B_H(0, 1, 1); STAGE_B_H(1, 1, 1);
    STAGE_A_Q(0, 1, 1); STAGE_A_Q(1, 1, 1);
    asm volatile("s_waitcnt vmcnt(8)" ::: "memory");   // B(0),A(0) landed
    __builtin_amdgcn_s_barrier();
    READ_A(a03, 0, (const char*)As);      // a03(0)
    READ_B(b01A, 0, (const char*)Bs);     // b01(0)

    for (int tt = 0; tt < 30; tt += 6) {
        TILEBODY(tt + 0, 0, 0, 1, 1, 2, b01A, b01B);
        TILEBODY(tt + 1, 1, 1, 0, 2, 0, b01B, b01A);
        TILEBODY(tt + 2, 0, 2, 1, 0, 1, b01A, b01B);
        TILEBODY(tt + 3, 1, 0, 0, 1, 2, b01B, b01A);
        TILEBODY(tt + 4, 0, 1, 1, 2, 0, b01A, b01B);
        TILEBODY(tt + 5, 1, 2, 0, 0, 1, b01B, b01A);
    }
    TILEBODY(30, 0, 0, 1, 1, 2, b01A, b01B);
    TILEBODY(31, 1, 1, 0, 2, 0, b01B, b01A);
#undef TILEBODY
#undef CLUMP
#undef MFMAQ
#undef READ_A
#undef READ_B
#undef STAGE_A_Q
#undef STAGE_B_H

    // ---- fused LSTM gate epilogue (r1/r6-verified 256^2 mapping) ----------
    // acc[i][g][r]: row = tileM*256 + wr*128 + i*16 + (lane>>4)*4 + r,
    // gate g, logical j = (tileN*4+wc)*16 + (lane&15)
    const int j = ((tileN * 4 + wc) << 4) | fr;
    const float bi  = bh[j];
    const float bff = bh[j + 1024];
    const float bg  = bh[j + 2048];
    const float bo  = bh[j + 3072];

    const int row0 = tileM * 256 + wr * 128 + (lane >> 4) * 4;

    float cv[8][4];
    #pragma unroll
    for (int i = 0; i < 8; ++i)
        #pragma unroll
        for (int r = 0; r < 4; ++r)
            cv[i][r] = c[(size_t)(row0 + i * 16 + r) * KH + j];

    #pragma unroll
    for (int i = 0; i < 8; ++i) {
        #pragma unroll
        for (int r = 0; r < 4; ++r) {
            const size_t idx = (size_t)(row0 + i * 16 + r) * KH + j;
            float iv = fsig(acc[i][0][r] + bi);
            float fv = fsig(acc[i][1][r] + bff);
            float gv = ftanh(acc[i][2][r] + bg);
            float ov = fsig(acc[i][3][r] + bo);
            float cn = fv * cv[i][r] + iv * gv;
            float hn = ov * ftanh(cn);
            out[idx] = hn;
            out[(size_t)ARR_ELEMS + idx] = cn;
        }
    }
}

// ----------------------------------------------------------------- launch ---
extern "C" void kernel_launch(void* const* d_in, const int* in_sizes, int n_in,
                              void* d_out, int out_size, void* d_ws, size_t ws_size,
                              hipStream_t stream) {
    const float* x  = (const float*)d_in[0];
    const float* h  = (const float*)d_in[1];
    const float* c  = (const float*)d_in[2];
    const float* Wh = (const float*)d_in[3];
    const float* bh = (const float*)d_in[4];
    const float* Wx = (const float*)d_in[5];
    float* out = (float*)d_out;

    unsigned short* ws   = (unsigned short*)d_ws;
    unsigned short* Acat = ws;
    unsigned short* Wcat = ws + 2 * (size_t)ARR_ELEMS;

    convert_kernel<<<8192, 256, 0, stream>>>(h, x, Wh, Wx, Acat, Wcat);
    gemm_kernel<<<256, 512, 0, stream>>>(Acat, Wcat, bh, c, out);
}